// Round 3
// baseline (1314.561 us; speedup 1.0000x reference)
//
#include <hip/hip_runtime.h>
#include <stdint.h>

#define N_NODES 10000
#define E_EDGES 160000
#define DIN 128
#define H 1024
#define NUM_GRAPHS 8
#define LN_EPS 1e-5f

typedef unsigned short u16;
typedef __attribute__((ext_vector_type(8))) short short8;
typedef __attribute__((ext_vector_type(4))) float f32x4;

__device__ __forceinline__ float bf2f(u16 v) { return __uint_as_float(((unsigned)v) << 16); }
__device__ __forceinline__ u16 f2bf(float f) {
    unsigned u = __float_as_uint(f);
    u += 0x7fffu + ((u >> 16) & 1u);
    return (u16)(u >> 16);
}

// ---------------- CSR build ----------------
__global__ void k_init(int* cnt, int* gstart, int* gend, int* gcnt) {
    int i = blockIdx.x * 256 + threadIdx.x;
    if (i < N_NODES) cnt[i] = 0;
    if (i < NUM_GRAPHS) { gstart[i] = 0x7fffffff; gend[i] = 0; gcnt[i] = 0; }
}

__global__ void k_count(const int* __restrict__ dst, int* __restrict__ cnt) {
    int e = blockIdx.x * 256 + threadIdx.x;
    if (e < E_EDGES) atomicAdd(&cnt[dst[e]], 1);
}

__global__ __launch_bounds__(1024) void k_scan(const int* __restrict__ cnt, int* __restrict__ offs,
                                               int* __restrict__ cursor, float* __restrict__ dinv) {
    __shared__ int s[1024];
    __shared__ int carry_s;
    int tid = threadIdx.x;
    if (tid == 0) carry_s = 0;
    __syncthreads();
    for (int base = 0; base < N_NODES; base += 1024) {
        int i = base + tid;
        int v = (i < N_NODES) ? cnt[i] : 0;
        s[tid] = v;
        __syncthreads();
        for (int off = 1; off < 1024; off <<= 1) {
            int t = (tid >= off) ? s[tid - off] : 0;
            __syncthreads();
            s[tid] += t;
            __syncthreads();
        }
        int incl = s[tid];
        int excl = incl - v;
        int cbase = carry_s;
        if (i < N_NODES) {
            offs[i] = cbase + excl;
            cursor[i] = cbase + excl;
            dinv[i] = rsqrtf((float)(v + 1));  // in-degree + self loop, always >= 1
        }
        __syncthreads();
        if (tid == 1023) carry_s = cbase + incl;
        __syncthreads();
    }
    if (tid == 0) offs[N_NODES] = carry_s;
}

__global__ void k_fill(const int* __restrict__ src, const int* __restrict__ dst,
                       int* __restrict__ cursor, int* __restrict__ csr_src) {
    int e = blockIdx.x * 256 + threadIdx.x;
    if (e < E_EDGES) {
        int d = dst[e];
        int slot = atomicAdd(&cursor[d], 1);
        csr_src[slot] = src[e];
    }
}

// ---------------- f32 -> bf16 convert ----------------
__global__ void k_cvt(const float* __restrict__ src, u16* __restrict__ dst, int n) {
    int i = blockIdx.x * 256 + threadIdx.x;
    if (i < n) dst[i] = f2bf(src[i]);
}

// ---------------- weight transpose+convert: f32 [R,C] -> bf16 [C,R] ----------------
__global__ void k_transpose_cvt(const float* __restrict__ src, u16* __restrict__ dst, int R, int C) {
    __shared__ float tile[32][33];
    int tx = threadIdx.x, ty = threadIdx.y;
    int x = blockIdx.x * 32 + tx;
#pragma unroll
    for (int i = 0; i < 32; i += 8) {
        int y = blockIdx.y * 32 + ty + i;
        tile[ty + i][tx] = (y < R && x < C) ? src[(size_t)y * C + x] : 0.f;
    }
    __syncthreads();
    int xo = blockIdx.y * 32 + tx;
#pragma unroll
    for (int i = 0; i < 32; i += 8) {
        int yo = blockIdx.x * 32 + ty + i;
        if (yo < C && xo < R) dst[(size_t)yo * R + xo] = f2bf(tile[tx][ty + i]);
    }
}

// ---------------- MFMA GEMM: C[M,Nn] = A[M,K] * B[Nn,K]^T, bf16 in, bf16 out, f32 accum ----------------
__global__ __launch_bounds__(256) void k_gemm(const u16* __restrict__ A, const u16* __restrict__ B,
                                              u16* __restrict__ C, int M, int Nn, int K) {
    __shared__ __align__(16) u16 sA[128 * 32];
    __shared__ __align__(16) u16 sB[128 * 32];
    int tid = threadIdx.x;
    int lane = tid & 63;
    int w = tid >> 6;
    int wm = w >> 1, wn = w & 1;
    int m0 = blockIdx.x * 128;
    int n0 = blockIdx.y * 128;

    f32x4 zero = {0.f, 0.f, 0.f, 0.f};
    f32x4 acc[4][4];
#pragma unroll
    for (int i = 0; i < 4; i++)
#pragma unroll
        for (int j = 0; j < 4; j++) acc[i][j] = zero;

    int trow = tid >> 2;
    int tcol = (tid & 3) * 8;
    short8 zv = {0, 0, 0, 0, 0, 0, 0, 0};

    for (int k0 = 0; k0 < K; k0 += 32) {
        int ra0 = m0 + trow, ra1 = m0 + trow + 64;
        short8 a0 = (ra0 < M) ? *(const short8*)(A + (size_t)ra0 * K + k0 + tcol) : zv;
        short8 a1 = (ra1 < M) ? *(const short8*)(A + (size_t)ra1 * K + k0 + tcol) : zv;
        short8 b0 = *(const short8*)(B + (size_t)(n0 + trow) * K + k0 + tcol);
        short8 b1 = *(const short8*)(B + (size_t)(n0 + trow + 64) * K + k0 + tcol);
        __syncthreads();
        *(short8*)(sA + trow * 32 + tcol) = a0;
        *(short8*)(sA + (trow + 64) * 32 + tcol) = a1;
        *(short8*)(sB + trow * 32 + tcol) = b0;
        *(short8*)(sB + (trow + 64) * 32 + tcol) = b1;
        __syncthreads();

        short8 af[4], bv[4];
#pragma unroll
        for (int mi = 0; mi < 4; mi++)
            af[mi] = *(const short8*)(sA + (wm * 64 + mi * 16 + (lane & 15)) * 32 + (lane >> 4) * 8);
#pragma unroll
        for (int ni = 0; ni < 4; ni++)
            bv[ni] = *(const short8*)(sB + (wn * 64 + ni * 16 + (lane & 15)) * 32 + (lane >> 4) * 8);
#pragma unroll
        for (int mi = 0; mi < 4; mi++)
#pragma unroll
            for (int ni = 0; ni < 4; ni++)
                acc[mi][ni] = __builtin_amdgcn_mfma_f32_16x16x32_bf16(af[mi], bv[ni], acc[mi][ni], 0, 0, 0);
    }

    int rbase = m0 + wm * 64 + (lane >> 4) * 4;
    int cbase = n0 + wn * 64 + (lane & 15);
#pragma unroll
    for (int mi = 0; mi < 4; mi++) {
#pragma unroll
        for (int r = 0; r < 4; r++) {
            int row = rbase + mi * 16 + r;
            if (row < M) {
#pragma unroll
                for (int ni = 0; ni < 4; ni++)
                    C[(size_t)row * Nn + cbase + ni * 16] = f2bf(acc[mi][ni][r]);
            }
        }
    }
}

// ---------------- fused GCN-aggregate + bias + residual + LayerNorm + ReLU ----------------
// xsum[d] = dinv[d]*(sum_{s in N(d)} dinv[s]*t[s] + dinv[d]*t[d]) + bias (+ resid)
// MODE 0: no resid; store pre-LN xsum to out_pre (bf16) and post-LN to out_bf.
// MODE 1: + resid (bf16); post-LN to out_bf.
// MODE 2: + resid (bf16); post-LN to out_f32 (FINAL, float32 output).
template <int MODE>
__global__ __launch_bounds__(256) void k_agg_ln(const u16* __restrict__ t, const u16* __restrict__ resid,
                                                const float* __restrict__ bias, const float* __restrict__ gamma,
                                                const float* __restrict__ beta, const float* __restrict__ dinv,
                                                const int* __restrict__ offs, const int* __restrict__ csr_src,
                                                u16* __restrict__ out_bf, u16* __restrict__ out_pre,
                                                float* __restrict__ out_f32) {
    __shared__ float s_dv[256];
    __shared__ int s_id[256];
    __shared__ float red1[4], red2[4];
    int d = blockIdx.x;
    int tid = threadIdx.x;
    int c = tid * 4;
    float dd = dinv[d];

    float a0, a1, a2, a3;
    {
        ushort4 v = *(const ushort4*)(t + (size_t)d * H + c);
        a0 = dd * bf2f(v.x); a1 = dd * bf2f(v.y); a2 = dd * bf2f(v.z); a3 = dd * bf2f(v.w);
    }
    int beg = offs[d], end = offs[d + 1];
    for (int chunk = beg; chunk < end; chunk += 256) {
        int nthis = end - chunk;
        if (nthis > 256) nthis = 256;
        __syncthreads();
        if (tid < nthis) {
            int s = csr_src[chunk + tid];
            s_id[tid] = s;
            s_dv[tid] = dinv[s];
        }
        __syncthreads();
        for (int i = 0; i < nthis; i++) {
            int s = s_id[i];
            float ds = s_dv[i];
            ushort4 v = *(const ushort4*)(t + (size_t)s * H + c);
            a0 += ds * bf2f(v.x); a1 += ds * bf2f(v.y); a2 += ds * bf2f(v.z); a3 += ds * bf2f(v.w);
        }
    }
    float x0 = dd * a0 + bias[c + 0];
    float x1 = dd * a1 + bias[c + 1];
    float x2 = dd * a2 + bias[c + 2];
    float x3 = dd * a3 + bias[c + 3];
    if (MODE >= 1) {
        ushort4 r = *(const ushort4*)(resid + (size_t)d * H + c);
        x0 += bf2f(r.x); x1 += bf2f(r.y); x2 += bf2f(r.z); x3 += bf2f(r.w);
    }
    if (MODE == 0) {
        ushort4 p;
        p.x = f2bf(x0); p.y = f2bf(x1); p.z = f2bf(x2); p.w = f2bf(x3);
        *(ushort4*)(out_pre + (size_t)d * H + c) = p;
    }
    float s1 = x0 + x1 + x2 + x3;
    float s2 = x0 * x0 + x1 * x1 + x2 * x2 + x3 * x3;
#pragma unroll
    for (int off = 32; off > 0; off >>= 1) {
        s1 += __shfl_down(s1, off);
        s2 += __shfl_down(s2, off);
    }
    int lane = tid & 63, wv = tid >> 6;
    if (lane == 0) { red1[wv] = s1; red2[wv] = s2; }
    __syncthreads();
    float sum = red1[0] + red1[1] + red1[2] + red1[3];
    float ssq = red2[0] + red2[1] + red2[2] + red2[3];
    float mean = sum * (1.f / H);
    float var = fmaxf(ssq * (1.f / H) - mean * mean, 0.f);
    float inv = rsqrtf(var + LN_EPS);
    float y0 = fmaxf((x0 - mean) * inv * gamma[c + 0] + beta[c + 0], 0.f);
    float y1 = fmaxf((x1 - mean) * inv * gamma[c + 1] + beta[c + 1], 0.f);
    float y2 = fmaxf((x2 - mean) * inv * gamma[c + 2] + beta[c + 2], 0.f);
    float y3 = fmaxf((x3 - mean) * inv * gamma[c + 3] + beta[c + 3], 0.f);
    if (MODE == 2) {
        float4 o = {y0, y1, y2, y3};
        *(float4*)(out_f32 + (size_t)d * H + c) = o;
    } else {
        ushort4 o;
        o.x = f2bf(y0); o.y = f2bf(y1); o.z = f2bf(y2); o.w = f2bf(y3);
        *(ushort4*)(out_bf + (size_t)d * H + c) = o;
    }
}

// ---------------- pooling + MLP head (all f32) ----------------
__global__ void k_bounds(const int* __restrict__ batch, int* gstart, int* gend, int* gcnt) {
    int i = blockIdx.x * 256 + threadIdx.x;
    if (i >= N_NODES) return;
    int b = batch[i];
    atomicAdd(&gcnt[b], 1);
    atomicMin(&gstart[b], i);
    atomicMax(&gend[b], i + 1);
}

__global__ __launch_bounds__(256) void k_pool(const float* __restrict__ ne, const int* __restrict__ gstart,
                                              const int* __restrict__ gend, const int* __restrict__ gcnt,
                                              float* __restrict__ v0, float* __restrict__ ge_out) {
    int g = blockIdx.y;
    int c = blockIdx.x * 256 + threadIdx.x;
    int a = gstart[g], b = gend[g];
    float s = 0.f;
    for (int n = a; n < b; n++) s += ne[(size_t)n * H + c];
    float m = s / fmaxf((float)gcnt[g], 1.f);
    v0[g * H + c] = m;
    ge_out[(size_t)g * H + c] = m;
}

__global__ __launch_bounds__(256) void k_mlp(const float* __restrict__ vin, const float* __restrict__ W,
                                             const float* __restrict__ bias, float* __restrict__ vout) {
    int g = blockIdx.y;
    int j = blockIdx.x * 256 + threadIdx.x;
    __shared__ float sv[H];
    for (int i = threadIdx.x; i < H; i += 256) sv[i] = vin[g * H + i];
    __syncthreads();
    float acc = 0.f;
#pragma unroll 8
    for (int k = 0; k < H; k++) acc += sv[k] * W[(size_t)k * H + j];
    acc += bias[j];
    vout[g * H + j] = fmaxf(acc, 0.f);
}

__global__ void k_head(const float* __restrict__ vin, const float* __restrict__ Wo,
                       const float* __restrict__ bo, float* __restrict__ out) {
    int g = blockIdx.x;
    int tid = threadIdx.x;
    float s = 0.f;
    for (int k = tid; k < H; k += 256) s += vin[g * H + k] * Wo[k];
#pragma unroll
    for (int off = 32; off > 0; off >>= 1) s += __shfl_down(s, off);
    __shared__ float p[4];
    if ((tid & 63) == 0) p[tid >> 6] = s;
    __syncthreads();
    if (tid == 0) out[g] = p[0] + p[1] + p[2] + p[3] + bo[0];
}

extern "C" void kernel_launch(void* const* d_in, const int* in_sizes, int n_in,
                              void* d_out, int out_size, void* d_ws, size_t ws_size,
                              hipStream_t stream) {
    const float* x = (const float*)d_in[0];
    const int* ei = (const int*)d_in[1];
    const int* batch = (const int*)d_in[2];
    const float* W1 = (const float*)d_in[3];
    const float* b1 = (const float*)d_in[4];
    const float* Wh = (const float*)d_in[5];
    const float* bh = (const float*)d_in[6];
    const float* ln_g = (const float*)d_in[7];
    const float* ln_b = (const float*)d_in[8];
    const float* vW = (const float*)d_in[9];
    const float* vb = (const float*)d_in[10];
    const float* vWo = (const float*)d_in[11];
    const float* vbo = (const float*)d_in[12];
    const int* esrc = ei;
    const int* edst = ei + E_EDGES;

    char* ws = (char*)d_ws;
    size_t off = 0;
    auto carve = [&](size_t bytes) -> char* {
        char* p = ws + off;
        off += (bytes + 255) & ~(size_t)255;
        return p;
    };
    float* dinv = (float*)carve(N_NODES * 4);
    int* cnt = (int*)carve(N_NODES * 4);
    int* offs = (int*)carve((N_NODES + 1) * 4);
    int* cursor = (int*)carve(N_NODES * 4);
    int* csr_src = (int*)carve(E_EDGES * 4);
    int* gstart = (int*)carve(NUM_GRAPHS * 4);
    int* gend = (int*)carve(NUM_GRAPHS * 4);
    int* gcnt = (int*)carve(NUM_GRAPHS * 4);
    float* v0 = (float*)carve(NUM_GRAPHS * H * 4);
    float* v1 = (float*)carve(NUM_GRAPHS * H * 4);
    u16* xb = (u16*)carve((size_t)N_NODES * DIN * 2);   // x cast to bf16
    u16* Wt = (u16*)carve((size_t)H * H * 2);           // transposed bf16 weight (reused per layer)
    u16* tbuf = (u16*)carve((size_t)N_NODES * H * 2);   // GEMM output (bf16)
    u16* hbuf = (u16*)carve((size_t)N_NODES * H * 2);   // post-LN activations (bf16)
    u16* x1buf = (u16*)carve((size_t)N_NODES * H * 2);  // x1 residual (bf16)

    float* out_ne = (float*)d_out;
    float* out_ge = out_ne + (size_t)N_NODES * H;
    float* out_sv = out_ge + (size_t)NUM_GRAPHS * H;

    k_init<<<(N_NODES + 255) / 256, 256, 0, stream>>>(cnt, gstart, gend, gcnt);
    k_count<<<(E_EDGES + 255) / 256, 256, 0, stream>>>(edst, cnt);
    k_scan<<<1, 1024, 0, stream>>>(cnt, offs, cursor, dinv);
    k_fill<<<(E_EDGES + 255) / 256, 256, 0, stream>>>(esrc, edst, cursor, csr_src);
    k_cvt<<<(N_NODES * DIN + 255) / 256, 256, 0, stream>>>(x, xb, N_NODES * DIN);

    dim3 tb(32, 8);
    dim3 gg((N_NODES + 127) / 128, H / 128);

    // layer 1: x1 = gcn(x,W1,b1); h1 = relu(LN0(x1)); keep pre-LN x1
    k_transpose_cvt<<<dim3(H / 32, DIN / 32), tb, 0, stream>>>(W1, Wt, DIN, H);
    k_gemm<<<gg, 256, 0, stream>>>(xb, Wt, tbuf, N_NODES, H, DIN);
    k_agg_ln<0><<<N_NODES, 256, 0, stream>>>(tbuf, nullptr, b1, ln_g, ln_b, dinv, offs, csr_src,
                                             hbuf, x1buf, nullptr);

    // layer 2: h2 = relu(LN1(gcn(h1,Wh0,bh0) + x1))
    k_transpose_cvt<<<dim3(H / 32, H / 32), tb, 0, stream>>>(Wh + 0 * (size_t)H * H, Wt, H, H);
    k_gemm<<<gg, 256, 0, stream>>>(hbuf, Wt, tbuf, N_NODES, H, H);
    k_agg_ln<1><<<N_NODES, 256, 0, stream>>>(tbuf, x1buf, bh, ln_g + H, ln_b + H, dinv, offs, csr_src,
                                             hbuf, nullptr, nullptr);

    // layer 3: h3 = relu(LN2(gcn(h2,Wh1,bh1) + x1))
    k_transpose_cvt<<<dim3(H / 32, H / 32), tb, 0, stream>>>(Wh + 1 * (size_t)H * H, Wt, H, H);
    k_gemm<<<gg, 256, 0, stream>>>(hbuf, Wt, tbuf, N_NODES, H, H);
    k_agg_ln<1><<<N_NODES, 256, 0, stream>>>(tbuf, x1buf, bh + H, ln_g + 2 * H, ln_b + 2 * H, dinv, offs, csr_src,
                                             hbuf, nullptr, nullptr);

    // layer 4: node_embeddings = relu(LN3(gcn(h3,Wh2,bh2) + h3))  -> f32 d_out
    k_transpose_cvt<<<dim3(H / 32, H / 32), tb, 0, stream>>>(Wh + 2 * (size_t)H * H, Wt, H, H);
    k_gemm<<<gg, 256, 0, stream>>>(hbuf, Wt, tbuf, N_NODES, H, H);
    k_agg_ln<2><<<N_NODES, 256, 0, stream>>>(tbuf, hbuf, bh + 2 * H, ln_g + 3 * H, ln_b + 3 * H, dinv, offs, csr_src,
                                             nullptr, nullptr, out_ne);

    k_bounds<<<(N_NODES + 255) / 256, 256, 0, stream>>>(batch, gstart, gend, gcnt);
    k_pool<<<dim3(H / 256, NUM_GRAPHS), 256, 0, stream>>>(out_ne, gstart, gend, gcnt, v0, out_ge);

    float* vin = v0;
    float* vout = v1;
    for (int i = 0; i < 6; i++) {
        k_mlp<<<dim3(H / 256, NUM_GRAPHS), 256, 0, stream>>>(vin, vW + (size_t)i * H * H, vb + (size_t)i * H, vout);
        float* tmp = vin; vin = vout; vout = tmp;
    }
    k_head<<<NUM_GRAPHS, 256, 0, stream>>>(vin, vWo, vbo, out_sv);
}

// Round 4
// 699.924 us; speedup vs baseline: 1.8781x; 1.8781x over previous
//
#include <hip/hip_runtime.h>
#include <stdint.h>

#define N_NODES 10000
#define E_EDGES 160000
#define DIN 128
#define H 1024
#define NUM_GRAPHS 8
#define LN_EPS 1e-5f

typedef unsigned short u16;
typedef __attribute__((ext_vector_type(8))) short short8;
typedef __attribute__((ext_vector_type(4))) float f32x4;

__device__ __forceinline__ float bf2f(u16 v) { return __uint_as_float(((unsigned)v) << 16); }
__device__ __forceinline__ u16 f2bf(float f) {
    unsigned u = __float_as_uint(f);
    u += 0x7fffu + ((u >> 16) & 1u);
    return (u16)(u >> 16);
}

// ---------------- init: counters, graph sums, MLP bias pre-init ----------------
// vbuf layout: 7 buffers of [NUM_GRAPHS][H] f32; v0 filled by pool, v1..v6 init to vb[0..5]
__global__ void k_init(int* cnt, int* gcnt, float* __restrict__ gsum,
                       float* __restrict__ vbuf, const float* __restrict__ vb) {
    int i = blockIdx.x * 256 + threadIdx.x;
    if (i < N_NODES) cnt[i] = 0;
    if (i < NUM_GRAPHS) gcnt[i] = 0;
    if (i < NUM_GRAPHS * H) gsum[i] = 0.f;
    if (i < 6 * H) {
        int il = i >> 10, j = i & (H - 1);
        float b = vb[il * H + j];
        float* base = vbuf + (size_t)(il + 1) * NUM_GRAPHS * H;
#pragma unroll
        for (int g = 0; g < NUM_GRAPHS; g++) base[g * H + j] = b;
    }
}

__global__ void k_count(const int* __restrict__ dst, int* __restrict__ cnt) {
    int e = blockIdx.x * 256 + threadIdx.x;
    if (e < E_EDGES) atomicAdd(&cnt[dst[e]], 1);
}

__global__ __launch_bounds__(1024) void k_scan(const int* __restrict__ cnt, int* __restrict__ offs,
                                               int* __restrict__ cursor, float* __restrict__ dinv) {
    __shared__ int s[1024];
    __shared__ int carry_s;
    int tid = threadIdx.x;
    if (tid == 0) carry_s = 0;
    __syncthreads();
    for (int base = 0; base < N_NODES; base += 1024) {
        int i = base + tid;
        int v = (i < N_NODES) ? cnt[i] : 0;
        s[tid] = v;
        __syncthreads();
        for (int off = 1; off < 1024; off <<= 1) {
            int t = (tid >= off) ? s[tid - off] : 0;
            __syncthreads();
            s[tid] += t;
            __syncthreads();
        }
        int incl = s[tid];
        int excl = incl - v;
        int cbase = carry_s;
        if (i < N_NODES) {
            offs[i] = cbase + excl;
            cursor[i] = cbase + excl;
            dinv[i] = rsqrtf((float)(v + 1));  // in-degree + self loop, always >= 1
        }
        __syncthreads();
        if (tid == 1023) carry_s = cbase + incl;
        __syncthreads();
    }
    if (tid == 0) offs[N_NODES] = carry_s;
}

__global__ void k_fill(const int* __restrict__ src, const int* __restrict__ dst,
                       int* __restrict__ cursor, int* __restrict__ csr_src) {
    int e = blockIdx.x * 256 + threadIdx.x;
    if (e < E_EDGES) {
        int d = dst[e];
        int slot = atomicAdd(&cursor[d], 1);
        csr_src[slot] = src[e];
    }
}

__global__ void k_gcnt(const int* __restrict__ batch, int* gcnt) {
    int i = blockIdx.x * 256 + threadIdx.x;
    if (i < N_NODES) atomicAdd(&gcnt[batch[i]], 1);
}

// ---------------- f32 -> bf16 convert ----------------
__global__ void k_cvt(const float* __restrict__ src, u16* __restrict__ dst, int n) {
    int i = blockIdx.x * 256 + threadIdx.x;
    if (i < n) dst[i] = f2bf(src[i]);
}

// ---------------- weight transpose+convert: f32 [R,C] -> bf16 [C,R] ----------------
__global__ void k_transpose_cvt(const float* __restrict__ src, u16* __restrict__ dst, int R, int C) {
    __shared__ float tile[32][33];
    int tx = threadIdx.x, ty = threadIdx.y;
    int x = blockIdx.x * 32 + tx;
#pragma unroll
    for (int i = 0; i < 32; i += 8) {
        int y = blockIdx.y * 32 + ty + i;
        tile[ty + i][tx] = (y < R && x < C) ? src[(size_t)y * C + x] : 0.f;
    }
    __syncthreads();
    int xo = blockIdx.y * 32 + tx;
#pragma unroll
    for (int i = 0; i < 32; i += 8) {
        int yo = blockIdx.x * 32 + ty + i;
        if (yo < C && xo < R) dst[(size_t)yo * R + xo] = f2bf(tile[tx][ty + i]);
    }
}

// ---------------- MFMA GEMM: C[M,Nn] = A[M,K] * B[Nn,K]^T, bf16, f32 accum ----------------
// m97-style async staging: global_load_lds width=16, wave-uniform LDS base + lane*16.
typedef __attribute__((address_space(1))) const unsigned int gas_u32;
typedef __attribute__((address_space(3))) unsigned int las_u32;
__device__ __forceinline__ void gld_lds16(const void* g, void* l) {
    __builtin_amdgcn_global_load_lds((gas_u32*)g, (las_u32*)l, 16, 0, 0);
}

__global__ __launch_bounds__(256) void k_gemm(const u16* __restrict__ A, const u16* __restrict__ B,
                                              u16* __restrict__ C, int M, int Nn, int K) {
    __shared__ __align__(16) u16 sA[128 * 32];
    __shared__ __align__(16) u16 sB[128 * 32];
    int tid = threadIdx.x;
    int lane = tid & 63;
    int w = tid >> 6;
    int wm = w >> 1, wn = w & 1;
    int m0 = blockIdx.x * 128;
    int n0 = blockIdx.y * 128;

    f32x4 zero = {0.f, 0.f, 0.f, 0.f};
    f32x4 acc[4][4];
#pragma unroll
    for (int i = 0; i < 4; i++)
#pragma unroll
        for (int j = 0; j < 4; j++) acc[i][j] = zero;

    // wave w stages rows [w*32, w*32+32): lane L -> row w*32 + q*16 + (L>>2), col (L&3)*8.
    // LDS dest = wave base (w*1024 elems) + q*512 + L*8 elems  == base + lane*16 bytes. ✓
    int srow = w * 32 + (lane >> 2);
    int scol = (lane & 3) * 8;
    u16* laA = sA + w * 1024;
    u16* laB = sB + w * 1024;

    for (int k0 = 0; k0 < K; k0 += 32) {
        __syncthreads();  // previous iteration's fragment reads complete
#pragma unroll
        for (int q = 0; q < 2; q++) {
            int rA = m0 + srow + q * 16;
            rA = rA < M ? rA : M - 1;  // clamp tail (stores predicated)
            gld_lds16(A + (size_t)rA * K + k0 + scol, laA + q * 512);
            gld_lds16(B + (size_t)(n0 + srow + q * 16) * K + k0 + scol, laB + q * 512);
        }
        __syncthreads();  // drains vmcnt -> staged data visible

        short8 af[4], bv[4];
#pragma unroll
        for (int mi = 0; mi < 4; mi++)
            af[mi] = *(const short8*)(sA + (wm * 64 + mi * 16 + (lane & 15)) * 32 + (lane >> 4) * 8);
#pragma unroll
        for (int ni = 0; ni < 4; ni++)
            bv[ni] = *(const short8*)(sB + (wn * 64 + ni * 16 + (lane & 15)) * 32 + (lane >> 4) * 8);
#pragma unroll
        for (int mi = 0; mi < 4; mi++)
#pragma unroll
            for (int ni = 0; ni < 4; ni++)
                acc[mi][ni] = __builtin_amdgcn_mfma_f32_16x16x32_bf16(af[mi], bv[ni], acc[mi][ni], 0, 0, 0);
    }

    int rbase = m0 + wm * 64 + (lane >> 4) * 4;
    int cbase = n0 + wn * 64 + (lane & 15);
#pragma unroll
    for (int mi = 0; mi < 4; mi++) {
#pragma unroll
        for (int r = 0; r < 4; r++) {
            int row = rbase + mi * 16 + r;
            if (row < M) {
#pragma unroll
                for (int ni = 0; ni < 4; ni++)
                    C[(size_t)row * Nn + cbase + ni * 16] = f2bf(acc[mi][ni][r]);
            }
        }
    }
}

// ---------------- fused GCN-aggregate + bias + residual + LayerNorm + ReLU ----------------
template <int MODE>
__global__ __launch_bounds__(256) void k_agg_ln(const u16* __restrict__ t, const u16* __restrict__ resid,
                                                const float* __restrict__ bias, const float* __restrict__ gamma,
                                                const float* __restrict__ beta, const float* __restrict__ dinv,
                                                const int* __restrict__ offs, const int* __restrict__ csr_src,
                                                u16* __restrict__ out_bf, u16* __restrict__ out_pre,
                                                float* __restrict__ out_f32) {
    __shared__ float s_dv[256];
    __shared__ int s_id[256];
    __shared__ float red1[4], red2[4];
    int d = blockIdx.x;
    int tid = threadIdx.x;
    int c = tid * 4;
    float dd = dinv[d];

    float a0, a1, a2, a3;
    {
        ushort4 v = *(const ushort4*)(t + (size_t)d * H + c);
        a0 = dd * bf2f(v.x); a1 = dd * bf2f(v.y); a2 = dd * bf2f(v.z); a3 = dd * bf2f(v.w);
    }
    int beg = offs[d], end = offs[d + 1];
    for (int chunk = beg; chunk < end; chunk += 256) {
        int nthis = end - chunk;
        if (nthis > 256) nthis = 256;
        __syncthreads();
        if (tid < nthis) {
            int s = csr_src[chunk + tid];
            s_id[tid] = s;
            s_dv[tid] = dinv[s];
        }
        __syncthreads();
        for (int i = 0; i < nthis; i++) {
            int s = s_id[i];
            float ds = s_dv[i];
            ushort4 v = *(const ushort4*)(t + (size_t)s * H + c);
            a0 += ds * bf2f(v.x); a1 += ds * bf2f(v.y); a2 += ds * bf2f(v.z); a3 += ds * bf2f(v.w);
        }
    }
    float x0 = dd * a0 + bias[c + 0];
    float x1 = dd * a1 + bias[c + 1];
    float x2 = dd * a2 + bias[c + 2];
    float x3 = dd * a3 + bias[c + 3];
    if (MODE >= 1) {
        ushort4 r = *(const ushort4*)(resid + (size_t)d * H + c);
        x0 += bf2f(r.x); x1 += bf2f(r.y); x2 += bf2f(r.z); x3 += bf2f(r.w);
    }
    if (MODE == 0) {
        ushort4 p;
        p.x = f2bf(x0); p.y = f2bf(x1); p.z = f2bf(x2); p.w = f2bf(x3);
        *(ushort4*)(out_pre + (size_t)d * H + c) = p;
    }
    float s1 = x0 + x1 + x2 + x3;
    float s2 = x0 * x0 + x1 * x1 + x2 * x2 + x3 * x3;
#pragma unroll
    for (int off = 32; off > 0; off >>= 1) {
        s1 += __shfl_down(s1, off);
        s2 += __shfl_down(s2, off);
    }
    int lane = tid & 63, wv = tid >> 6;
    if (lane == 0) { red1[wv] = s1; red2[wv] = s2; }
    __syncthreads();
    float sum = red1[0] + red1[1] + red1[2] + red1[3];
    float ssq = red2[0] + red2[1] + red2[2] + red2[3];
    float mean = sum * (1.f / H);
    float var = fmaxf(ssq * (1.f / H) - mean * mean, 0.f);
    float inv = rsqrtf(var + LN_EPS);
    float y0 = fmaxf((x0 - mean) * inv * gamma[c + 0] + beta[c + 0], 0.f);
    float y1 = fmaxf((x1 - mean) * inv * gamma[c + 1] + beta[c + 1], 0.f);
    float y2 = fmaxf((x2 - mean) * inv * gamma[c + 2] + beta[c + 2], 0.f);
    float y3 = fmaxf((x3 - mean) * inv * gamma[c + 3] + beta[c + 3], 0.f);
    if (MODE == 2) {
        float4 o = {y0, y1, y2, y3};
        *(float4*)(out_f32 + (size_t)d * H + c) = o;
    } else {
        ushort4 o;
        o.x = f2bf(y0); o.y = f2bf(y1); o.z = f2bf(y2); o.w = f2bf(y3);
        *(ushort4*)(out_bf + (size_t)d * H + c) = o;
    }
}

// ---------------- parallel mean-pool ----------------
#define PC_NODES 200
__global__ __launch_bounds__(256) void k_pool_acc(const float* __restrict__ ne, const int* __restrict__ batch,
                                                  float* __restrict__ gsum) {
    int c = blockIdx.x * 256 + threadIdx.x;
    int nbeg = blockIdx.y * PC_NODES;
    int nend = nbeg + PC_NODES;
    if (nend > N_NODES) nend = N_NODES;
    float acc = 0.f;
    int curg = batch[nbeg];
    for (int n = nbeg; n < nend; n++) {
        int g = batch[n];  // wave-uniform broadcast (batch sorted)
        if (g != curg) {
            atomicAdd(&gsum[curg * H + c], acc);
            acc = 0.f;
            curg = g;
        }
        acc += ne[(size_t)n * H + c];
    }
    atomicAdd(&gsum[curg * H + c], acc);
}

__global__ __launch_bounds__(256) void k_pool_fin(const float* __restrict__ gsum, const int* __restrict__ gcnt,
                                                  float* __restrict__ v0, float* __restrict__ ge_out) {
    int g = blockIdx.y;
    int c = blockIdx.x * 256 + threadIdx.x;
    float m = gsum[g * H + c] / fmaxf((float)gcnt[g], 1.f);
    v0[g * H + c] = m;
    ge_out[(size_t)g * H + c] = m;
}

// ---------------- split-K MLP: vout (pre-init to bias) += vin(@relu?) @ W ----------------
template <bool RELU_IN>
__global__ __launch_bounds__(256) void k_mlp_acc(const float* __restrict__ vin, const float* __restrict__ W,
                                                 float* __restrict__ vout) {
    __shared__ float sk[64];
    int g = blockIdx.y;
    int j = blockIdx.x * 256 + threadIdx.x;
    int k0 = blockIdx.z * 64;
    if (threadIdx.x < 64) {
        float v = vin[g * H + k0 + threadIdx.x];
        sk[threadIdx.x] = RELU_IN ? fmaxf(v, 0.f) : v;
    }
    __syncthreads();
    float acc = 0.f;
#pragma unroll
    for (int k = 0; k < 64; k++) acc += sk[k] * W[(size_t)(k0 + k) * H + j];
    atomicAdd(&vout[g * H + j], acc);
}

__global__ void k_head(const float* __restrict__ vin, const float* __restrict__ Wo,
                       const float* __restrict__ bo, float* __restrict__ out) {
    int g = blockIdx.x;
    int tid = threadIdx.x;
    float s = 0.f;
    for (int k = tid; k < H; k += 256) s += fmaxf(vin[g * H + k], 0.f) * Wo[k];
#pragma unroll
    for (int off = 32; off > 0; off >>= 1) s += __shfl_down(s, off);
    __shared__ float p[4];
    if ((tid & 63) == 0) p[tid >> 6] = s;
    __syncthreads();
    if (tid == 0) out[g] = p[0] + p[1] + p[2] + p[3] + bo[0];
}

extern "C" void kernel_launch(void* const* d_in, const int* in_sizes, int n_in,
                              void* d_out, int out_size, void* d_ws, size_t ws_size,
                              hipStream_t stream) {
    const float* x = (const float*)d_in[0];
    const int* ei = (const int*)d_in[1];
    const int* batch = (const int*)d_in[2];
    const float* W1 = (const float*)d_in[3];
    const float* b1 = (const float*)d_in[4];
    const float* Wh = (const float*)d_in[5];
    const float* bh = (const float*)d_in[6];
    const float* ln_g = (const float*)d_in[7];
    const float* ln_b = (const float*)d_in[8];
    const float* vW = (const float*)d_in[9];
    const float* vb = (const float*)d_in[10];
    const float* vWo = (const float*)d_in[11];
    const float* vbo = (const float*)d_in[12];
    const int* esrc = ei;
    const int* edst = ei + E_EDGES;

    char* ws = (char*)d_ws;
    size_t off = 0;
    auto carve = [&](size_t bytes) -> char* {
        char* p = ws + off;
        off += (bytes + 255) & ~(size_t)255;
        return p;
    };
    float* dinv = (float*)carve(N_NODES * 4);
    int* cnt = (int*)carve(N_NODES * 4);
    int* offs = (int*)carve((N_NODES + 1) * 4);
    int* cursor = (int*)carve(N_NODES * 4);
    int* csr_src = (int*)carve(E_EDGES * 4);
    int* gcnt = (int*)carve(NUM_GRAPHS * 4);
    float* gsum = (float*)carve(NUM_GRAPHS * H * 4);
    float* vbuf = (float*)carve((size_t)7 * NUM_GRAPHS * H * 4);  // v0..v6
    u16* xb = (u16*)carve((size_t)N_NODES * DIN * 2);
    u16* Wt = (u16*)carve((size_t)H * H * 2);
    u16* tbuf = (u16*)carve((size_t)N_NODES * H * 2);
    u16* hbuf = (u16*)carve((size_t)N_NODES * H * 2);
    u16* x1buf = (u16*)carve((size_t)N_NODES * H * 2);

    float* out_ne = (float*)d_out;
    float* out_ge = out_ne + (size_t)N_NODES * H;
    float* out_sv = out_ge + (size_t)NUM_GRAPHS * H;

    k_init<<<(N_NODES + 255) / 256, 256, 0, stream>>>(cnt, gcnt, gsum, vbuf, vb);
    k_count<<<(E_EDGES + 255) / 256, 256, 0, stream>>>(edst, cnt);
    k_scan<<<1, 1024, 0, stream>>>(cnt, offs, cursor, dinv);
    k_fill<<<(E_EDGES + 255) / 256, 256, 0, stream>>>(esrc, edst, cursor, csr_src);
    k_gcnt<<<(N_NODES + 255) / 256, 256, 0, stream>>>(batch, gcnt);
    k_cvt<<<(N_NODES * DIN + 255) / 256, 256, 0, stream>>>(x, xb, N_NODES * DIN);

    dim3 tb(32, 8);
    dim3 gg((N_NODES + 127) / 128, H / 128);

    // layer 1: x1 = gcn(x,W1,b1); h1 = relu(LN0(x1)); keep pre-LN x1
    k_transpose_cvt<<<dim3(H / 32, DIN / 32), tb, 0, stream>>>(W1, Wt, DIN, H);
    k_gemm<<<gg, 256, 0, stream>>>(xb, Wt, tbuf, N_NODES, H, DIN);
    k_agg_ln<0><<<N_NODES, 256, 0, stream>>>(tbuf, nullptr, b1, ln_g, ln_b, dinv, offs, csr_src,
                                             hbuf, x1buf, nullptr);

    // layer 2: h2 = relu(LN1(gcn(h1,Wh0,bh0) + x1))
    k_transpose_cvt<<<dim3(H / 32, H / 32), tb, 0, stream>>>(Wh + 0 * (size_t)H * H, Wt, H, H);
    k_gemm<<<gg, 256, 0, stream>>>(hbuf, Wt, tbuf, N_NODES, H, H);
    k_agg_ln<1><<<N_NODES, 256, 0, stream>>>(tbuf, x1buf, bh, ln_g + H, ln_b + H, dinv, offs, csr_src,
                                             hbuf, nullptr, nullptr);

    // layer 3: h3 = relu(LN2(gcn(h2,Wh1,bh1) + x1))
    k_transpose_cvt<<<dim3(H / 32, H / 32), tb, 0, stream>>>(Wh + 1 * (size_t)H * H, Wt, H, H);
    k_gemm<<<gg, 256, 0, stream>>>(hbuf, Wt, tbuf, N_NODES, H, H);
    k_agg_ln<1><<<N_NODES, 256, 0, stream>>>(tbuf, x1buf, bh + H, ln_g + 2 * H, ln_b + 2 * H, dinv, offs, csr_src,
                                             hbuf, nullptr, nullptr);

    // layer 4: node_embeddings -> f32 d_out
    k_transpose_cvt<<<dim3(H / 32, H / 32), tb, 0, stream>>>(Wh + 2 * (size_t)H * H, Wt, H, H);
    k_gemm<<<gg, 256, 0, stream>>>(hbuf, Wt, tbuf, N_NODES, H, H);
    k_agg_ln<2><<<N_NODES, 256, 0, stream>>>(tbuf, hbuf, bh + 2 * H, ln_g + 3 * H, ln_b + 3 * H, dinv, offs, csr_src,
                                             nullptr, nullptr, out_ne);

    // mean pool (parallel) -> v0 and out_ge
    k_pool_acc<<<dim3(H / 256, (N_NODES + PC_NODES - 1) / PC_NODES), 256, 0, stream>>>(out_ne, batch, gsum);
    k_pool_fin<<<dim3(H / 256, NUM_GRAPHS), 256, 0, stream>>>(gsum, gcnt, vbuf, out_ge);

    // MLP head: v_{i+1} (pre-init to bias) += relu?(v_i) @ vW_i
    dim3 mg(H / 256, NUM_GRAPHS, 16);
    k_mlp_acc<false><<<mg, 256, 0, stream>>>(vbuf, vW, vbuf + (size_t)1 * NUM_GRAPHS * H);
    for (int i = 1; i < 6; i++)
        k_mlp_acc<true><<<mg, 256, 0, stream>>>(vbuf + (size_t)i * NUM_GRAPHS * H, vW + (size_t)i * H * H,
                                                vbuf + (size_t)(i + 1) * NUM_GRAPHS * H);
    k_head<<<NUM_GRAPHS, 256, 0, stream>>>(vbuf + (size_t)6 * NUM_GRAPHS * H, vWo, vbo, out_sv);
}

// Round 5
// 582.844 us; speedup vs baseline: 2.2554x; 1.2009x over previous
//
#include <hip/hip_runtime.h>
#include <stdint.h>

#define N_NODES 10000
#define E_EDGES 160000
#define DIN 128
#define H 1024
#define NUM_GRAPHS 8
#define LN_EPS 1e-5f

typedef unsigned short u16;
typedef __attribute__((ext_vector_type(8))) short short8;
typedef __attribute__((ext_vector_type(4))) float f32x4;

__device__ __forceinline__ float bf2f(u16 v) { return __uint_as_float(((unsigned)v) << 16); }
__device__ __forceinline__ u16 f2bf(float f) {
    unsigned u = __float_as_uint(f);
    u += 0x7fffu + ((u >> 16) & 1u);
    return (u16)(u >> 16);
}

// ---------------- init: counters, graph sums, graph offsets, MLP bias pre-init ----------------
// vbuf layout: 7 buffers of [NUM_GRAPHS][H] f32; v0 filled by pool, v1..v6 init to vb[0..5]
__global__ void k_init(int* cnt, int* goff, float* __restrict__ gsum,
                       float* __restrict__ vbuf, const float* __restrict__ vb) {
    int i = blockIdx.x * 256 + threadIdx.x;
    if (i < N_NODES) cnt[i] = 0;
    if (i <= NUM_GRAPHS) goff[i] = 0;  // boundary-scan kernel fills nonzero entries
    if (i < NUM_GRAPHS * H) gsum[i] = 0.f;
    if (i < 6 * H) {
        int il = i >> 10, j = i & (H - 1);
        float b = vb[il * H + j];
        float* base = vbuf + (size_t)(il + 1) * NUM_GRAPHS * H;
#pragma unroll
        for (int g = 0; g < NUM_GRAPHS; g++) base[g * H + j] = b;
    }
}

__global__ void k_count(const int* __restrict__ dst, int* __restrict__ cnt) {
    int e = blockIdx.x * 256 + threadIdx.x;
    if (e < E_EDGES) atomicAdd(&cnt[dst[e]], 1);
}

__global__ __launch_bounds__(1024) void k_scan(const int* __restrict__ cnt, int* __restrict__ offs,
                                               int* __restrict__ cursor, float* __restrict__ dinv) {
    __shared__ int s[1024];
    __shared__ int carry_s;
    int tid = threadIdx.x;
    if (tid == 0) carry_s = 0;
    __syncthreads();
    for (int base = 0; base < N_NODES; base += 1024) {
        int i = base + tid;
        int v = (i < N_NODES) ? cnt[i] : 0;
        s[tid] = v;
        __syncthreads();
        for (int off = 1; off < 1024; off <<= 1) {
            int t = (tid >= off) ? s[tid - off] : 0;
            __syncthreads();
            s[tid] += t;
            __syncthreads();
        }
        int incl = s[tid];
        int excl = incl - v;
        int cbase = carry_s;
        if (i < N_NODES) {
            offs[i] = cbase + excl;
            cursor[i] = cbase + excl;
            dinv[i] = rsqrtf((float)(v + 1));  // in-degree + self loop, always >= 1
        }
        __syncthreads();
        if (tid == 1023) carry_s = cbase + incl;
        __syncthreads();
    }
    if (tid == 0) offs[N_NODES] = carry_s;
}

__global__ void k_fill(const int* __restrict__ src, const int* __restrict__ dst,
                       int* __restrict__ cursor, int* __restrict__ csr_src) {
    int e = blockIdx.x * 256 + threadIdx.x;
    if (e < E_EDGES) {
        int d = dst[e];
        int slot = atomicAdd(&cursor[d], 1);
        csr_src[slot] = src[e];
    }
}

// ---------------- graph boundaries from sorted batch (no atomics) ----------------
// goff[g] = first index i with batch[i] >= g; goff pre-zeroed in k_init.
__global__ void k_gbound(const int* __restrict__ batch, int* __restrict__ goff) {
    int i = blockIdx.x * 256 + threadIdx.x;
    if (i >= N_NODES) return;
    int b0 = batch[i];
    int b1 = (i + 1 < N_NODES) ? batch[i + 1] : NUM_GRAPHS;
    for (int g = b0 + 1; g <= b1; g++) goff[g] = i + 1;  // executes only at boundaries
}

// ---------------- f32 -> bf16 convert ----------------
__global__ void k_cvt(const float* __restrict__ src, u16* __restrict__ dst, int n) {
    int i = blockIdx.x * 256 + threadIdx.x;
    if (i < n) dst[i] = f2bf(src[i]);
}

// ---------------- weight transpose+convert: f32 [R,C] -> bf16 [C,R] ----------------
__global__ void k_transpose_cvt(const float* __restrict__ src, u16* __restrict__ dst, int R, int C) {
    __shared__ float tile[32][33];
    int tx = threadIdx.x, ty = threadIdx.y;
    int x = blockIdx.x * 32 + tx;
#pragma unroll
    for (int i = 0; i < 32; i += 8) {
        int y = blockIdx.y * 32 + ty + i;
        tile[ty + i][tx] = (y < R && x < C) ? src[(size_t)y * C + x] : 0.f;
    }
    __syncthreads();
    int xo = blockIdx.y * 32 + tx;
#pragma unroll
    for (int i = 0; i < 32; i += 8) {
        int yo = blockIdx.x * 32 + ty + i;
        if (yo < C && xo < R) dst[(size_t)yo * R + xo] = f2bf(tile[tx][ty + i]);
    }
}

// ---------------- MFMA GEMM: C[M,Nn] = A[M,K] * B[Nn,K]^T, bf16, f32 accum ----------------
typedef __attribute__((address_space(1))) const unsigned int gas_u32;
typedef __attribute__((address_space(3))) unsigned int las_u32;
__device__ __forceinline__ void gld_lds16(const void* g, void* l) {
    __builtin_amdgcn_global_load_lds((gas_u32*)g, (las_u32*)l, 16, 0, 0);
}

__global__ __launch_bounds__(256) void k_gemm(const u16* __restrict__ A, const u16* __restrict__ B,
                                              u16* __restrict__ C, int M, int Nn, int K) {
    __shared__ __align__(16) u16 sA[128 * 32];
    __shared__ __align__(16) u16 sB[128 * 32];
    int tid = threadIdx.x;
    int lane = tid & 63;
    int w = tid >> 6;
    int wm = w >> 1, wn = w & 1;
    int m0 = blockIdx.x * 128;
    int n0 = blockIdx.y * 128;

    f32x4 zero = {0.f, 0.f, 0.f, 0.f};
    f32x4 acc[4][4];
#pragma unroll
    for (int i = 0; i < 4; i++)
#pragma unroll
        for (int j = 0; j < 4; j++) acc[i][j] = zero;

    int srow = w * 32 + (lane >> 2);
    int scol = (lane & 3) * 8;
    u16* laA = sA + w * 1024;
    u16* laB = sB + w * 1024;

    for (int k0 = 0; k0 < K; k0 += 32) {
        __syncthreads();
#pragma unroll
        for (int q = 0; q < 2; q++) {
            int rA = m0 + srow + q * 16;
            rA = rA < M ? rA : M - 1;
            gld_lds16(A + (size_t)rA * K + k0 + scol, laA + q * 512);
            gld_lds16(B + (size_t)(n0 + srow + q * 16) * K + k0 + scol, laB + q * 512);
        }
        __syncthreads();

        short8 af[4], bv[4];
#pragma unroll
        for (int mi = 0; mi < 4; mi++)
            af[mi] = *(const short8*)(sA + (wm * 64 + mi * 16 + (lane & 15)) * 32 + (lane >> 4) * 8);
#pragma unroll
        for (int ni = 0; ni < 4; ni++)
            bv[ni] = *(const short8*)(sB + (wn * 64 + ni * 16 + (lane & 15)) * 32 + (lane >> 4) * 8);
#pragma unroll
        for (int mi = 0; mi < 4; mi++)
#pragma unroll
            for (int ni = 0; ni < 4; ni++)
                acc[mi][ni] = __builtin_amdgcn_mfma_f32_16x16x32_bf16(af[mi], bv[ni], acc[mi][ni], 0, 0, 0);
    }

    int rbase = m0 + wm * 64 + (lane >> 4) * 4;
    int cbase = n0 + wn * 64 + (lane & 15);
#pragma unroll
    for (int mi = 0; mi < 4; mi++) {
#pragma unroll
        for (int r = 0; r < 4; r++) {
            int row = rbase + mi * 16 + r;
            if (row < M) {
#pragma unroll
                for (int ni = 0; ni < 4; ni++)
                    C[(size_t)row * Nn + cbase + ni * 16] = f2bf(acc[mi][ni][r]);
            }
        }
    }
}

// ---------------- fused GCN-aggregate + bias + residual + LayerNorm + ReLU ----------------
template <int MODE>
__global__ __launch_bounds__(256) void k_agg_ln(const u16* __restrict__ t, const u16* __restrict__ resid,
                                                const float* __restrict__ bias, const float* __restrict__ gamma,
                                                const float* __restrict__ beta, const float* __restrict__ dinv,
                                                const int* __restrict__ offs, const int* __restrict__ csr_src,
                                                u16* __restrict__ out_bf, u16* __restrict__ out_pre,
                                                float* __restrict__ out_f32) {
    __shared__ float s_dv[256];
    __shared__ int s_id[256];
    __shared__ float red1[4], red2[4];
    int d = blockIdx.x;
    int tid = threadIdx.x;
    int c = tid * 4;
    float dd = dinv[d];

    float a0, a1, a2, a3;
    {
        ushort4 v = *(const ushort4*)(t + (size_t)d * H + c);
        a0 = dd * bf2f(v.x); a1 = dd * bf2f(v.y); a2 = dd * bf2f(v.z); a3 = dd * bf2f(v.w);
    }
    int beg = offs[d], end = offs[d + 1];
    for (int chunk = beg; chunk < end; chunk += 256) {
        int nthis = end - chunk;
        if (nthis > 256) nthis = 256;
        __syncthreads();
        if (tid < nthis) {
            int s = csr_src[chunk + tid];
            s_id[tid] = s;
            s_dv[tid] = dinv[s];
        }
        __syncthreads();
        for (int i = 0; i < nthis; i++) {
            int s = s_id[i];
            float ds = s_dv[i];
            ushort4 v = *(const ushort4*)(t + (size_t)s * H + c);
            a0 += ds * bf2f(v.x); a1 += ds * bf2f(v.y); a2 += ds * bf2f(v.z); a3 += ds * bf2f(v.w);
        }
    }
    float x0 = dd * a0 + bias[c + 0];
    float x1 = dd * a1 + bias[c + 1];
    float x2 = dd * a2 + bias[c + 2];
    float x3 = dd * a3 + bias[c + 3];
    if (MODE >= 1) {
        ushort4 r = *(const ushort4*)(resid + (size_t)d * H + c);
        x0 += bf2f(r.x); x1 += bf2f(r.y); x2 += bf2f(r.z); x3 += bf2f(r.w);
    }
    if (MODE == 0) {
        ushort4 p;
        p.x = f2bf(x0); p.y = f2bf(x1); p.z = f2bf(x2); p.w = f2bf(x3);
        *(ushort4*)(out_pre + (size_t)d * H + c) = p;
    }
    float s1 = x0 + x1 + x2 + x3;
    float s2 = x0 * x0 + x1 * x1 + x2 * x2 + x3 * x3;
#pragma unroll
    for (int off = 32; off > 0; off >>= 1) {
        s1 += __shfl_down(s1, off);
        s2 += __shfl_down(s2, off);
    }
    int lane = tid & 63, wv = tid >> 6;
    if (lane == 0) { red1[wv] = s1; red2[wv] = s2; }
    __syncthreads();
    float sum = red1[0] + red1[1] + red1[2] + red1[3];
    float ssq = red2[0] + red2[1] + red2[2] + red2[3];
    float mean = sum * (1.f / H);
    float var = fmaxf(ssq * (1.f / H) - mean * mean, 0.f);
    float inv = rsqrtf(var + LN_EPS);
    float y0 = fmaxf((x0 - mean) * inv * gamma[c + 0] + beta[c + 0], 0.f);
    float y1 = fmaxf((x1 - mean) * inv * gamma[c + 1] + beta[c + 1], 0.f);
    float y2 = fmaxf((x2 - mean) * inv * gamma[c + 2] + beta[c + 2], 0.f);
    float y3 = fmaxf((x3 - mean) * inv * gamma[c + 3] + beta[c + 3], 0.f);
    if (MODE == 2) {
        float4 o = {y0, y1, y2, y3};
        *(float4*)(out_f32 + (size_t)d * H + c) = o;
    } else {
        ushort4 o;
        o.x = f2bf(y0); o.y = f2bf(y1); o.z = f2bf(y2); o.w = f2bf(y3);
        *(ushort4*)(out_bf + (size_t)d * H + c) = o;
    }
}

// ---------------- parallel mean-pool ----------------
#define PC_NODES 200
__global__ __launch_bounds__(256) void k_pool_acc(const float* __restrict__ ne, const int* __restrict__ batch,
                                                  float* __restrict__ gsum) {
    int c = blockIdx.x * 256 + threadIdx.x;
    int nbeg = blockIdx.y * PC_NODES;
    int nend = nbeg + PC_NODES;
    if (nend > N_NODES) nend = N_NODES;
    float acc = 0.f;
    int curg = batch[nbeg];
    for (int n = nbeg; n < nend; n++) {
        int g = batch[n];  // wave-uniform broadcast (batch sorted)
        if (g != curg) {
            atomicAdd(&gsum[curg * H + c], acc);
            acc = 0.f;
            curg = g;
        }
        acc += ne[(size_t)n * H + c];
    }
    atomicAdd(&gsum[curg * H + c], acc);
}

__global__ __launch_bounds__(256) void k_pool_fin(const float* __restrict__ gsum, const int* __restrict__ goff,
                                                  float* __restrict__ v0, float* __restrict__ ge_out) {
    int g = blockIdx.y;
    int c = blockIdx.x * 256 + threadIdx.x;
    float cntf = (float)(goff[g + 1] - goff[g]);
    float m = gsum[g * H + c] / fmaxf(cntf, 1.f);
    v0[g * H + c] = m;
    ge_out[(size_t)g * H + c] = m;
}

// ---------------- split-K MLP: vout (pre-init to bias) += relu?(vin) @ W ----------------
template <bool RELU_IN>
__global__ __launch_bounds__(256) void k_mlp_acc(const float* __restrict__ vin, const float* __restrict__ W,
                                                 float* __restrict__ vout) {
    __shared__ float sk[64];
    int g = blockIdx.y;
    int j = blockIdx.x * 256 + threadIdx.x;
    int k0 = blockIdx.z * 64;
    if (threadIdx.x < 64) {
        float v = vin[g * H + k0 + threadIdx.x];
        sk[threadIdx.x] = RELU_IN ? fmaxf(v, 0.f) : v;
    }
    __syncthreads();
    float acc = 0.f;
#pragma unroll
    for (int k = 0; k < 64; k++) acc += sk[k] * W[(size_t)(k0 + k) * H + j];
    atomicAdd(&vout[g * H + j], acc);
}

__global__ void k_head(const float* __restrict__ vin, const float* __restrict__ Wo,
                       const float* __restrict__ bo, float* __restrict__ out) {
    int g = blockIdx.x;
    int tid = threadIdx.x;
    float s = 0.f;
    for (int k = tid; k < H; k += 256) s += fmaxf(vin[g * H + k], 0.f) * Wo[k];
#pragma unroll
    for (int off = 32; off > 0; off >>= 1) s += __shfl_down(s, off);
    __shared__ float p[4];
    if ((tid & 63) == 0) p[tid >> 6] = s;
    __syncthreads();
    if (tid == 0) out[g] = p[0] + p[1] + p[2] + p[3] + bo[0];
}

extern "C" void kernel_launch(void* const* d_in, const int* in_sizes, int n_in,
                              void* d_out, int out_size, void* d_ws, size_t ws_size,
                              hipStream_t stream) {
    const float* x = (const float*)d_in[0];
    const int* ei = (const int*)d_in[1];
    const int* batch = (const int*)d_in[2];
    const float* W1 = (const float*)d_in[3];
    const float* b1 = (const float*)d_in[4];
    const float* Wh = (const float*)d_in[5];
    const float* bh = (const float*)d_in[6];
    const float* ln_g = (const float*)d_in[7];
    const float* ln_b = (const float*)d_in[8];
    const float* vW = (const float*)d_in[9];
    const float* vb = (const float*)d_in[10];
    const float* vWo = (const float*)d_in[11];
    const float* vbo = (const float*)d_in[12];
    const int* esrc = ei;
    const int* edst = ei + E_EDGES;

    char* ws = (char*)d_ws;
    size_t off = 0;
    auto carve = [&](size_t bytes) -> char* {
        char* p = ws + off;
        off += (bytes + 255) & ~(size_t)255;
        return p;
    };
    float* dinv = (float*)carve(N_NODES * 4);
    int* cnt = (int*)carve(N_NODES * 4);
    int* offs = (int*)carve((N_NODES + 1) * 4);
    int* cursor = (int*)carve(N_NODES * 4);
    int* csr_src = (int*)carve(E_EDGES * 4);
    int* goff = (int*)carve((NUM_GRAPHS + 1) * 4);
    float* gsum = (float*)carve(NUM_GRAPHS * H * 4);
    float* vbuf = (float*)carve((size_t)7 * NUM_GRAPHS * H * 4);  // v0..v6
    u16* xb = (u16*)carve((size_t)N_NODES * DIN * 2);
    u16* Wt = (u16*)carve((size_t)H * H * 2);
    u16* tbuf = (u16*)carve((size_t)N_NODES * H * 2);
    u16* hbuf = (u16*)carve((size_t)N_NODES * H * 2);
    u16* x1buf = (u16*)carve((size_t)N_NODES * H * 2);

    float* out_ne = (float*)d_out;
    float* out_ge = out_ne + (size_t)N_NODES * H;
    float* out_sv = out_ge + (size_t)NUM_GRAPHS * H;

    k_init<<<(N_NODES + 255) / 256, 256, 0, stream>>>(cnt, goff, gsum, vbuf, vb);
    k_count<<<(E_EDGES + 255) / 256, 256, 0, stream>>>(edst, cnt);
    k_scan<<<1, 1024, 0, stream>>>(cnt, offs, cursor, dinv);
    k_fill<<<(E_EDGES + 255) / 256, 256, 0, stream>>>(esrc, edst, cursor, csr_src);
    k_gbound<<<(N_NODES + 255) / 256, 256, 0, stream>>>(batch, goff);
    k_cvt<<<(N_NODES * DIN + 255) / 256, 256, 0, stream>>>(x, xb, N_NODES * DIN);

    dim3 tb(32, 8);
    dim3 gg((N_NODES + 127) / 128, H / 128);

    // layer 1: x1 = gcn(x,W1,b1); h1 = relu(LN0(x1)); keep pre-LN x1
    k_transpose_cvt<<<dim3(H / 32, DIN / 32), tb, 0, stream>>>(W1, Wt, DIN, H);
    k_gemm<<<gg, 256, 0, stream>>>(xb, Wt, tbuf, N_NODES, H, DIN);
    k_agg_ln<0><<<N_NODES, 256, 0, stream>>>(tbuf, nullptr, b1, ln_g, ln_b, dinv, offs, csr_src,
                                             hbuf, x1buf, nullptr);

    // layer 2: h2 = relu(LN1(gcn(h1,Wh0,bh0) + x1))
    k_transpose_cvt<<<dim3(H / 32, H / 32), tb, 0, stream>>>(Wh + 0 * (size_t)H * H, Wt, H, H);
    k_gemm<<<gg, 256, 0, stream>>>(hbuf, Wt, tbuf, N_NODES, H, H);
    k_agg_ln<1><<<N_NODES, 256, 0, stream>>>(tbuf, x1buf, bh, ln_g + H, ln_b + H, dinv, offs, csr_src,
                                             hbuf, nullptr, nullptr);

    // layer 3: h3 = relu(LN2(gcn(h2,Wh1,bh1) + x1))
    k_transpose_cvt<<<dim3(H / 32, H / 32), tb, 0, stream>>>(Wh + 1 * (size_t)H * H, Wt, H, H);
    k_gemm<<<gg, 256, 0, stream>>>(hbuf, Wt, tbuf, N_NODES, H, H);
    k_agg_ln<1><<<N_NODES, 256, 0, stream>>>(tbuf, x1buf, bh + H, ln_g + 2 * H, ln_b + 2 * H, dinv, offs, csr_src,
                                             hbuf, nullptr, nullptr);

    // layer 4: node_embeddings -> f32 d_out
    k_transpose_cvt<<<dim3(H / 32, H / 32), tb, 0, stream>>>(Wh + 2 * (size_t)H * H, Wt, H, H);
    k_gemm<<<gg, 256, 0, stream>>>(hbuf, Wt, tbuf, N_NODES, H, H);
    k_agg_ln<2><<<N_NODES, 256, 0, stream>>>(tbuf, hbuf, bh + 2 * H, ln_g + 3 * H, ln_b + 3 * H, dinv, offs, csr_src,
                                             nullptr, nullptr, out_ne);

    // mean pool (parallel) -> v0 and out_ge
    k_pool_acc<<<dim3(H / 256, (N_NODES + PC_NODES - 1) / PC_NODES), 256, 0, stream>>>(out_ne, batch, gsum);
    k_pool_fin<<<dim3(H / 256, NUM_GRAPHS), 256, 0, stream>>>(gsum, goff, vbuf, out_ge);

    // MLP head: v_{i+1} (pre-init to bias) += relu?(v_i) @ vW_i
    dim3 mg(H / 256, NUM_GRAPHS, 16);
    k_mlp_acc<false><<<mg, 256, 0, stream>>>(vbuf, vW, vbuf + (size_t)1 * NUM_GRAPHS * H);
    for (int i = 1; i < 6; i++)
        k_mlp_acc<true><<<mg, 256, 0, stream>>>(vbuf + (size_t)i * NUM_GRAPHS * H, vW + (size_t)i * H * H,
                                                vbuf + (size_t)(i + 1) * NUM_GRAPHS * H);
    k_head<<<NUM_GRAPHS, 256, 0, stream>>>(vbuf + (size_t)6 * NUM_GRAPHS * H, vWo, vbo, out_sv);
}

// Round 6
// 536.642 us; speedup vs baseline: 2.4496x; 1.0861x over previous
//
#include <hip/hip_runtime.h>
#include <stdint.h>

#define N_NODES 10000
#define E_EDGES 160000
#define DIN 128
#define H 1024
#define NUM_GRAPHS 8
#define LN_EPS 1e-5f

typedef unsigned short u16;
typedef __attribute__((ext_vector_type(8))) short short8;
typedef __attribute__((ext_vector_type(8))) unsigned short ushort8v;
typedef __attribute__((ext_vector_type(4))) float f32x4;

__device__ __forceinline__ float bf2f(u16 v) { return __uint_as_float(((unsigned)v) << 16); }
__device__ __forceinline__ u16 f2bf(float f) {
    unsigned u = __float_as_uint(f);
    u += 0x7fffu + ((u >> 16) & 1u);
    return (u16)(u >> 16);
}

// ---------------- init: counters, graph sums, graph offsets, MLP bias pre-init ----------------
__global__ void k_init(int* cnt, int* goff, float* __restrict__ gsum,
                       float* __restrict__ vbuf, const float* __restrict__ vb) {
    int i = blockIdx.x * 256 + threadIdx.x;
    if (i < N_NODES) cnt[i] = 0;
    if (i <= NUM_GRAPHS) goff[i] = 0;
    if (i < NUM_GRAPHS * H) gsum[i] = 0.f;
    if (i < 6 * H) {
        int il = i >> 10, j = i & (H - 1);
        float b = vb[il * H + j];
        float* base = vbuf + (size_t)(il + 1) * NUM_GRAPHS * H;
#pragma unroll
        for (int g = 0; g < NUM_GRAPHS; g++) base[g * H + j] = b;
    }
}

__global__ void k_count(const int* __restrict__ dst, int* __restrict__ cnt) {
    int e = blockIdx.x * 256 + threadIdx.x;
    if (e < E_EDGES) atomicAdd(&cnt[dst[e]], 1);
}

__global__ __launch_bounds__(1024) void k_scan(const int* __restrict__ cnt, int* __restrict__ offs,
                                               int* __restrict__ cursor, float* __restrict__ dinv) {
    __shared__ int s[1024];
    __shared__ int carry_s;
    int tid = threadIdx.x;
    if (tid == 0) carry_s = 0;
    __syncthreads();
    for (int base = 0; base < N_NODES; base += 1024) {
        int i = base + tid;
        int v = (i < N_NODES) ? cnt[i] : 0;
        s[tid] = v;
        __syncthreads();
        for (int off = 1; off < 1024; off <<= 1) {
            int t = (tid >= off) ? s[tid - off] : 0;
            __syncthreads();
            s[tid] += t;
            __syncthreads();
        }
        int incl = s[tid];
        int excl = incl - v;
        int cbase = carry_s;
        if (i < N_NODES) {
            offs[i] = cbase + excl;
            cursor[i] = cbase + excl;
            dinv[i] = rsqrtf((float)(v + 1));
        }
        __syncthreads();
        if (tid == 1023) carry_s = cbase + incl;
        __syncthreads();
    }
    if (tid == 0) offs[N_NODES] = carry_s;
}

__global__ void k_fill(const int* __restrict__ src, const int* __restrict__ dst,
                       int* __restrict__ cursor, int* __restrict__ csr_src) {
    int e = blockIdx.x * 256 + threadIdx.x;
    if (e < E_EDGES) {
        int d = dst[e];
        int slot = atomicAdd(&cursor[d], 1);
        csr_src[slot] = src[e];
    }
}

// goff[g] = first index i with batch[i] >= g (batch sorted; goff pre-zeroed)
__global__ void k_gbound(const int* __restrict__ batch, int* __restrict__ goff) {
    int i = blockIdx.x * 256 + threadIdx.x;
    if (i >= N_NODES) return;
    int b0 = batch[i];
    int b1 = (i + 1 < N_NODES) ? batch[i + 1] : NUM_GRAPHS;
    for (int g = b0 + 1; g <= b1; g++) goff[g] = i + 1;
}

__global__ void k_cvt(const float* __restrict__ src, u16* __restrict__ dst, int n) {
    int i = blockIdx.x * 256 + threadIdx.x;
    if (i < n) dst[i] = f2bf(src[i]);
}

__global__ void k_transpose_cvt(const float* __restrict__ src, u16* __restrict__ dst, int R, int C) {
    __shared__ float tile[32][33];
    int tx = threadIdx.x, ty = threadIdx.y;
    int x = blockIdx.x * 32 + tx;
#pragma unroll
    for (int i = 0; i < 32; i += 8) {
        int y = blockIdx.y * 32 + ty + i;
        tile[ty + i][tx] = (y < R && x < C) ? src[(size_t)y * C + x] : 0.f;
    }
    __syncthreads();
    int xo = blockIdx.y * 32 + tx;
#pragma unroll
    for (int i = 0; i < 32; i += 8) {
        int yo = blockIdx.x * 32 + ty + i;
        if (yo < C && xo < R) dst[(size_t)yo * R + xo] = f2bf(tile[tx][ty + i]);
    }
}

// ---------------- MFMA GEMM: C[M,Nn] = A[M,K] * B[Nn,K]^T, bf16, f32 accum ----------------
typedef __attribute__((address_space(1))) const unsigned int gas_u32;
typedef __attribute__((address_space(3))) unsigned int las_u32;
__device__ __forceinline__ void gld_lds16(const void* g, void* l) {
    __builtin_amdgcn_global_load_lds((gas_u32*)g, (las_u32*)l, 16, 0, 0);
}

__global__ __launch_bounds__(256) void k_gemm(const u16* __restrict__ A, const u16* __restrict__ B,
                                              u16* __restrict__ C, int M, int Nn, int K) {
    __shared__ __align__(16) u16 sA[128 * 32];
    __shared__ __align__(16) u16 sB[128 * 32];
    int tid = threadIdx.x;
    int lane = tid & 63;
    int w = tid >> 6;
    int wm = w >> 1, wn = w & 1;
    int m0 = blockIdx.x * 128;
    int n0 = blockIdx.y * 128;

    f32x4 zero = {0.f, 0.f, 0.f, 0.f};
    f32x4 acc[4][4];
#pragma unroll
    for (int i = 0; i < 4; i++)
#pragma unroll
        for (int j = 0; j < 4; j++) acc[i][j] = zero;

    int srow = w * 32 + (lane >> 2);
    int scol = (lane & 3) * 8;
    u16* laA = sA + w * 1024;
    u16* laB = sB + w * 1024;

    for (int k0 = 0; k0 < K; k0 += 32) {
        __syncthreads();
#pragma unroll
        for (int q = 0; q < 2; q++) {
            int rA = m0 + srow + q * 16;
            rA = rA < M ? rA : M - 1;
            gld_lds16(A + (size_t)rA * K + k0 + scol, laA + q * 512);
            gld_lds16(B + (size_t)(n0 + srow + q * 16) * K + k0 + scol, laB + q * 512);
        }
        __syncthreads();

        short8 af[4], bv[4];
#pragma unroll
        for (int mi = 0; mi < 4; mi++)
            af[mi] = *(const short8*)(sA + (wm * 64 + mi * 16 + (lane & 15)) * 32 + (lane >> 4) * 8);
#pragma unroll
        for (int ni = 0; ni < 4; ni++)
            bv[ni] = *(const short8*)(sB + (wn * 64 + ni * 16 + (lane & 15)) * 32 + (lane >> 4) * 8);
#pragma unroll
        for (int mi = 0; mi < 4; mi++)
#pragma unroll
            for (int ni = 0; ni < 4; ni++)
                acc[mi][ni] = __builtin_amdgcn_mfma_f32_16x16x32_bf16(af[mi], bv[ni], acc[mi][ni], 0, 0, 0);
    }

    int rbase = m0 + wm * 64 + (lane >> 4) * 4;
    int cbase = n0 + wn * 64 + (lane & 15);
#pragma unroll
    for (int mi = 0; mi < 4; mi++) {
#pragma unroll
        for (int r = 0; r < 4; r++) {
            int row = rbase + mi * 16 + r;
            if (row < M) {
#pragma unroll
                for (int ni = 0; ni < 4; ni++)
                    C[(size_t)row * Nn + cbase + ni * 16] = f2bf(acc[mi][ni][r]);
            }
        }
    }
}

// ---------------- fused GCN-aggregate + bias + residual + LayerNorm + ReLU ----------------
// 128 threads/block (2 waves), 8 elems/lane, 16B loads.
template <int MODE>
__global__ __launch_bounds__(128) void k_agg_ln(const u16* __restrict__ t, const u16* __restrict__ resid,
                                                const float* __restrict__ bias, const float* __restrict__ gamma,
                                                const float* __restrict__ beta, const float* __restrict__ dinv,
                                                const int* __restrict__ offs, const int* __restrict__ csr_src,
                                                u16* __restrict__ out_bf, u16* __restrict__ out_pre,
                                                float* __restrict__ out_f32) {
    __shared__ float s_dv[128];
    __shared__ int s_id[128];
    __shared__ float red1[2], red2[2];
    int d = blockIdx.x;
    int tid = threadIdx.x;
    int c = tid * 8;
    float dd = dinv[d];

    float a[8];
    {
        ushort8v v = *(const ushort8v*)(t + (size_t)d * H + c);
#pragma unroll
        for (int i = 0; i < 8; i++) a[i] = dd * bf2f(v[i]);
    }
    int beg = offs[d], end = offs[d + 1];
    for (int chunk = beg; chunk < end; chunk += 128) {
        int nthis = end - chunk;
        if (nthis > 128) nthis = 128;
        __syncthreads();
        if (tid < nthis) {
            int s = csr_src[chunk + tid];
            s_id[tid] = s;
            s_dv[tid] = dinv[s];
        }
        __syncthreads();
        for (int i = 0; i < nthis; i++) {
            int s = s_id[i];
            float ds = s_dv[i];
            ushort8v v = *(const ushort8v*)(t + (size_t)s * H + c);
#pragma unroll
            for (int j = 0; j < 8; j++) a[j] += ds * bf2f(v[j]);
        }
    }
    float x[8];
#pragma unroll
    for (int i = 0; i < 8; i++) x[i] = dd * a[i] + bias[c + i];
    if (MODE >= 1) {
        ushort8v r = *(const ushort8v*)(resid + (size_t)d * H + c);
#pragma unroll
        for (int i = 0; i < 8; i++) x[i] += bf2f(r[i]);
    }
    if (MODE == 0) {
        ushort8v p;
#pragma unroll
        for (int i = 0; i < 8; i++) p[i] = f2bf(x[i]);
        *(ushort8v*)(out_pre + (size_t)d * H + c) = p;
    }
    float s1 = 0.f, s2 = 0.f;
#pragma unroll
    for (int i = 0; i < 8; i++) { s1 += x[i]; s2 += x[i] * x[i]; }
#pragma unroll
    for (int off = 32; off > 0; off >>= 1) {
        s1 += __shfl_down(s1, off);
        s2 += __shfl_down(s2, off);
    }
    int lane = tid & 63, wv = tid >> 6;
    if (lane == 0) { red1[wv] = s1; red2[wv] = s2; }
    __syncthreads();
    float sum = red1[0] + red1[1];
    float ssq = red2[0] + red2[1];
    float mean = sum * (1.f / H);
    float var = fmaxf(ssq * (1.f / H) - mean * mean, 0.f);
    float inv = rsqrtf(var + LN_EPS);
    float y[8];
#pragma unroll
    for (int i = 0; i < 8; i++)
        y[i] = fmaxf((x[i] - mean) * inv * gamma[c + i] + beta[c + i], 0.f);
    if (MODE == 2) {
        float4 o0 = {y[0], y[1], y[2], y[3]};
        float4 o1 = {y[4], y[5], y[6], y[7]};
        *(float4*)(out_f32 + (size_t)d * H + c) = o0;
        *(float4*)(out_f32 + (size_t)d * H + c + 4) = o1;
    } else {
        ushort8v o;
#pragma unroll
        for (int i = 0; i < 8; i++) o[i] = f2bf(y[i]);
        *(ushort8v*)(out_bf + (size_t)d * H + c) = o;
    }
}

// ---------------- parallel mean-pool ----------------
#define PC_NODES 16
__global__ __launch_bounds__(256) void k_pool_acc(const float* __restrict__ ne, const int* __restrict__ batch,
                                                  float* __restrict__ gsum) {
    int c = blockIdx.x * 256 + threadIdx.x;
    int nbeg = blockIdx.y * PC_NODES;
    int nend = nbeg + PC_NODES;
    if (nend > N_NODES) nend = N_NODES;
    float acc = 0.f;
    int curg = batch[nbeg];
    for (int n = nbeg; n < nend; n++) {
        int g = batch[n];  // wave-uniform broadcast (batch sorted)
        if (g != curg) {
            atomicAdd(&gsum[curg * H + c], acc);
            acc = 0.f;
            curg = g;
        }
        acc += ne[(size_t)n * H + c];
    }
    atomicAdd(&gsum[curg * H + c], acc);
}

__global__ __launch_bounds__(256) void k_pool_fin(const float* __restrict__ gsum, const int* __restrict__ goff,
                                                  float* __restrict__ v0, float* __restrict__ ge_out) {
    int g = blockIdx.y;
    int c = blockIdx.x * 256 + threadIdx.x;
    float cntf = (float)(goff[g + 1] - goff[g]);
    float m = gsum[g * H + c] / fmaxf(cntf, 1.f);
    v0[g * H + c] = m;
    ge_out[(size_t)g * H + c] = m;
}

// ---------------- split-K MLP: vout (pre-init to bias) += relu?(vin) @ W ----------------
template <bool RELU_IN>
__global__ __launch_bounds__(256) void k_mlp_acc(const float* __restrict__ vin, const float* __restrict__ W,
                                                 float* __restrict__ vout) {
    __shared__ float sk[64];
    int g = blockIdx.y;
    int j = blockIdx.x * 256 + threadIdx.x;
    int k0 = blockIdx.z * 64;
    if (threadIdx.x < 64) {
        float v = vin[g * H + k0 + threadIdx.x];
        sk[threadIdx.x] = RELU_IN ? fmaxf(v, 0.f) : v;
    }
    __syncthreads();
    float acc = 0.f;
#pragma unroll
    for (int k = 0; k < 64; k++) acc += sk[k] * W[(size_t)(k0 + k) * H + j];
    atomicAdd(&vout[g * H + j], acc);
}

__global__ void k_head(const float* __restrict__ vin, const float* __restrict__ Wo,
                       const float* __restrict__ bo, float* __restrict__ out) {
    int g = blockIdx.x;
    int tid = threadIdx.x;
    float s = 0.f;
    for (int k = tid; k < H; k += 256) s += fmaxf(vin[g * H + k], 0.f) * Wo[k];
#pragma unroll
    for (int off = 32; off > 0; off >>= 1) s += __shfl_down(s, off);
    __shared__ float p[4];
    if ((tid & 63) == 0) p[tid >> 6] = s;
    __syncthreads();
    if (tid == 0) out[g] = p[0] + p[1] + p[2] + p[3] + bo[0];
}

extern "C" void kernel_launch(void* const* d_in, const int* in_sizes, int n_in,
                              void* d_out, int out_size, void* d_ws, size_t ws_size,
                              hipStream_t stream) {
    const float* x = (const float*)d_in[0];
    const int* ei = (const int*)d_in[1];
    const int* batch = (const int*)d_in[2];
    const float* W1 = (const float*)d_in[3];
    const float* b1 = (const float*)d_in[4];
    const float* Wh = (const float*)d_in[5];
    const float* bh = (const float*)d_in[6];
    const float* ln_g = (const float*)d_in[7];
    const float* ln_b = (const float*)d_in[8];
    const float* vW = (const float*)d_in[9];
    const float* vb = (const float*)d_in[10];
    const float* vWo = (const float*)d_in[11];
    const float* vbo = (const float*)d_in[12];
    const int* esrc = ei;
    const int* edst = ei + E_EDGES;

    char* ws = (char*)d_ws;
    size_t off = 0;
    auto carve = [&](size_t bytes) -> char* {
        char* p = ws + off;
        off += (bytes + 255) & ~(size_t)255;
        return p;
    };
    float* dinv = (float*)carve(N_NODES * 4);
    int* cnt = (int*)carve(N_NODES * 4);
    int* offs = (int*)carve((N_NODES + 1) * 4);
    int* cursor = (int*)carve(N_NODES * 4);
    int* csr_src = (int*)carve(E_EDGES * 4);
    int* goff = (int*)carve((NUM_GRAPHS + 1) * 4);
    float* gsum = (float*)carve(NUM_GRAPHS * H * 4);
    float* vbuf = (float*)carve((size_t)7 * NUM_GRAPHS * H * 4);
    u16* xb = (u16*)carve((size_t)N_NODES * DIN * 2);
    u16* Wt = (u16*)carve((size_t)H * H * 2);
    u16* tbuf = (u16*)carve((size_t)N_NODES * H * 2);
    u16* hbuf = (u16*)carve((size_t)N_NODES * H * 2);
    u16* x1buf = (u16*)carve((size_t)N_NODES * H * 2);

    float* out_ne = (float*)d_out;
    float* out_ge = out_ne + (size_t)N_NODES * H;
    float* out_sv = out_ge + (size_t)NUM_GRAPHS * H;

    k_init<<<(N_NODES + 255) / 256, 256, 0, stream>>>(cnt, goff, gsum, vbuf, vb);
    k_count<<<(E_EDGES + 255) / 256, 256, 0, stream>>>(edst, cnt);
    k_scan<<<1, 1024, 0, stream>>>(cnt, offs, cursor, dinv);
    k_fill<<<(E_EDGES + 255) / 256, 256, 0, stream>>>(esrc, edst, cursor, csr_src);
    k_gbound<<<(N_NODES + 255) / 256, 256, 0, stream>>>(batch, goff);
    k_cvt<<<(N_NODES * DIN + 255) / 256, 256, 0, stream>>>(x, xb, N_NODES * DIN);

    dim3 tb(32, 8);
    dim3 gg((N_NODES + 127) / 128, H / 128);

    // layer 1
    k_transpose_cvt<<<dim3(H / 32, DIN / 32), tb, 0, stream>>>(W1, Wt, DIN, H);
    k_gemm<<<gg, 256, 0, stream>>>(xb, Wt, tbuf, N_NODES, H, DIN);
    k_agg_ln<0><<<N_NODES, 128, 0, stream>>>(tbuf, nullptr, b1, ln_g, ln_b, dinv, offs, csr_src,
                                             hbuf, x1buf, nullptr);

    // layer 2
    k_transpose_cvt<<<dim3(H / 32, H / 32), tb, 0, stream>>>(Wh + 0 * (size_t)H * H, Wt, H, H);
    k_gemm<<<gg, 256, 0, stream>>>(hbuf, Wt, tbuf, N_NODES, H, H);
    k_agg_ln<1><<<N_NODES, 128, 0, stream>>>(tbuf, x1buf, bh, ln_g + H, ln_b + H, dinv, offs, csr_src,
                                             hbuf, nullptr, nullptr);

    // layer 3
    k_transpose_cvt<<<dim3(H / 32, H / 32), tb, 0, stream>>>(Wh + 1 * (size_t)H * H, Wt, H, H);
    k_gemm<<<gg, 256, 0, stream>>>(hbuf, Wt, tbuf, N_NODES, H, H);
    k_agg_ln<1><<<N_NODES, 128, 0, stream>>>(tbuf, x1buf, bh + H, ln_g + 2 * H, ln_b + 2 * H, dinv, offs, csr_src,
                                             hbuf, nullptr, nullptr);

    // layer 4 -> f32 d_out
    k_transpose_cvt<<<dim3(H / 32, H / 32), tb, 0, stream>>>(Wh + 2 * (size_t)H * H, Wt, H, H);
    k_gemm<<<gg, 256, 0, stream>>>(hbuf, Wt, tbuf, N_NODES, H, H);
    k_agg_ln<2><<<N_NODES, 128, 0, stream>>>(tbuf, hbuf, bh + 2 * H, ln_g + 3 * H, ln_b + 3 * H, dinv, offs, csr_src,
                                             nullptr, nullptr, out_ne);

    // mean pool (2500 blocks)
    k_pool_acc<<<dim3(H / 256, (N_NODES + PC_NODES - 1) / PC_NODES), 256, 0, stream>>>(out_ne, batch, gsum);
    k_pool_fin<<<dim3(H / 256, NUM_GRAPHS), 256, 0, stream>>>(gsum, goff, vbuf, out_ge);

    // MLP head
    dim3 mg(H / 256, NUM_GRAPHS, 16);
    k_mlp_acc<false><<<mg, 256, 0, stream>>>(vbuf, vW, vbuf + (size_t)1 * NUM_GRAPHS * H);
    for (int i = 1; i < 6; i++)
        k_mlp_acc<true><<<mg, 256, 0, stream>>>(vbuf + (size_t)i * NUM_GRAPHS * H, vW + (size_t)i * H * H,
                                                vbuf + (size_t)(i + 1) * NUM_GRAPHS * H);
    k_head<<<NUM_GRAPHS, 256, 0, stream>>>(vbuf + (size_t)6 * NUM_GRAPHS * H, vWo, vbo, out_sv);
}